// Round 3
// baseline (375.990 us; speedup 1.0000x reference)
//
#include <hip/hip_runtime.h>
#include <stdint.h>

// MissModel: chain of 20 x Linear(64,64) == ONE affine map out = M x + v,
//   M = W19···W0,  v = sum of suffix-products of biases.
// Kernel 1 (compose, 1 block): runs the verified chain machinery on 64 basis
//   vectors + zero token in SPLIT bf16 (hi/lo, 3 MFMA products per step) ->
//   M to ~1e-5 accuracy; epilogue emits apply A-frags + v into d_ws.
// Kernel 2 (apply, grid-wide): out = M x + v, one bf16 MFMA layer, no LDS.
// Fragment index algebra (A-frag permutation F, B-frag repack, store) is
// identical to the R1/R2-verified chain kernel.

using short8  = __attribute__((ext_vector_type(8))) short;  // 8 bf16
using floatx4 = __attribute__((ext_vector_type(4))) float;  // MFMA 16x16 acc

#define N_TOK   524288
#define N_LAYER 20
// output-feature permutation baked into A-frag rows (verified in R1/R2)
#define FPERM(mt, m) (32 * ((mt) >> 1) + 8 * ((m) >> 2) + 4 * ((mt) & 1) + ((m) & 3))

#ifdef __has_builtin
#if __has_builtin(__builtin_amdgcn_cvt_pk_bf16_f32)
#define HAVE_CVT_PK_BF16 1
#endif
#endif

#ifdef HAVE_CVT_PK_BF16
typedef __bf16 bf16x2_t __attribute__((ext_vector_type(2)));
__device__ __forceinline__ uint32_t pk_bf16(float lo, float hi) {
  union { bf16x2_t v; uint32_t u; } c;
  c.v = __builtin_amdgcn_cvt_pk_bf16_f32(lo, hi);   // RNE, 1 VALU
  return c.u;
}
#else
__device__ __forceinline__ uint32_t pk_bf16(float lo, float hi) {
  uint32_t a = __float_as_uint(lo) + 0x8000u;
  uint32_t b = __float_as_uint(hi) + 0x8000u;
  return __builtin_amdgcn_perm(b, a, 0x07060302u);
}
#endif

__device__ __forceinline__ float upk_lo(uint32_t p) { return __uint_as_float(p << 16); }
__device__ __forceinline__ float upk_hi(uint32_t p) { return __uint_as_float(p & 0xffff0000u); }

__device__ __forceinline__ uint16_t bf16_rne(float f) {
  uint32_t u = __float_as_uint(f);
  u += 0x7fffu + ((u >> 16) & 1u);
  return (uint16_t)(u >> 16);
}

union BFrag { short8 v; uint32_t u[4]; };
union AFrag { short8 v; uint32_t u[4]; uint4 raw; };

// ---------------------------------------------------------------------------
// compose: 1 block, 128 threads (2 token-waves). Wave 0 tokens = I_64 columns,
// wave 1 tokens = 0 (carry v). Split-precision chain: state = Bh + Bl,
// weights = Ah + Al (gathered from fp32 W on the fly), 3 products per k-step.
// ---------------------------------------------------------------------------
__global__ __launch_bounds__(128, 1) void compose(
    const float* __restrict__ W, const float* __restrict__ bias,
    uint16_t* __restrict__ afrag, float* __restrict__ vout)
{
  __shared__ float comp[65][64];   // comp[t][i] = (M e_t + v)[i]; comp[64] = v

  const int tid  = threadIdx.x;
  const int twv  = tid >> 6;
  const int lane = tid & 63;
  const int tl   = lane & 15;
  const int q    = lane >> 4;

  // --- basis-vector state (hi = identity, lo = 0) ---
  BFrag Bh[4][2], Bl[4][2];
  #pragma unroll
  for (int tb = 0; tb < 4; tb++) {
    const int tok = twv * 64 + tb * 16 + tl;
    #pragma unroll
    for (int ks = 0; ks < 2; ks++)
      #pragma unroll
      for (int p = 0; p < 4; p++) {
        const int f0 = 32 * ks + 8 * q + 2 * p;
        Bh[tb][ks].u[p] = pk_bf16(tok == f0 ? 1.0f : 0.0f, tok == f0 + 1 ? 1.0f : 0.0f);
        Bl[tb][ks].u[p] = 0u;
      }
  }

  // raw prefetch buffers (fp32): 8 frags x 2 float4 + 4 bias float4 per layer
  floatx4 wr[2][8][2];
  floatx4 br[2][4];

  #define FETCH(L, buf)                                                          \
    {                                                                            \
      _Pragma("unroll") for (int mt = 0; mt < 4; mt++) {                         \
        const int r = FPERM(mt, tl);                                             \
        const float* base = W + (L) * 4096 + r * 64;                             \
        _Pragma("unroll") for (int ks = 0; ks < 2; ks++) {                       \
          wr[buf][mt * 2 + ks][0] = *(const floatx4*)(base + 32 * ks + 8 * q);   \
          wr[buf][mt * 2 + ks][1] = *(const floatx4*)(base + 32 * ks + 8 * q + 4);\
        }                                                                        \
        br[buf][mt] = *(const floatx4*)(bias + (L) * 64 + 32 * (mt >> 1) + 4 * (mt & 1) + 8 * q); \
      }                                                                          \
    }

  FETCH(0, 0);

  floatx4 acc[4][4];
  #pragma unroll 2
  for (int l = 0; l < N_LAYER; l++) {
    const int cur = l & 1;
    if (l + 1 < N_LAYER) FETCH(l + 1, cur ^ 1);

    // convert raw fp32 weights -> Ah/Al (hi + residual)
    AFrag Ah[8], Al[8];
    #pragma unroll
    for (int f = 0; f < 8; f++) {
      #pragma unroll
      for (int h = 0; h < 2; h++) {
        floatx4 a = wr[cur][f][h];
        uint32_t h0 = pk_bf16(a[0], a[1]);
        uint32_t h1 = pk_bf16(a[2], a[3]);
        Ah[f].u[2 * h]     = h0;
        Ah[f].u[2 * h + 1] = h1;
        Al[f].u[2 * h]     = pk_bf16(a[0] - upk_lo(h0), a[1] - upk_hi(h0));
        Al[f].u[2 * h + 1] = pk_bf16(a[2] - upk_lo(h1), a[3] - upk_hi(h1));
      }
    }

    // acc init = bias (same for every token: affine recurrence h' = W h + b)
    #pragma unroll
    for (int mt = 0; mt < 4; mt++)
      #pragma unroll
      for (int tb = 0; tb < 4; tb++) acc[tb][mt] = br[cur][mt];

    // 3-product split MFMA: W_hi*H_hi + W_hi*H_lo + W_lo*H_hi
    #pragma unroll
    for (int ks = 0; ks < 2; ks++)
      #pragma unroll
      for (int mt = 0; mt < 4; mt++) {
        const int f = mt * 2 + ks;
        #pragma unroll
        for (int tb = 0; tb < 4; tb++) {
          acc[tb][mt] = __builtin_amdgcn_mfma_f32_16x16x32_bf16(Ah[f].v, Bh[tb][ks].v, acc[tb][mt], 0, 0, 0);
          acc[tb][mt] = __builtin_amdgcn_mfma_f32_16x16x32_bf16(Ah[f].v, Bl[tb][ks].v, acc[tb][mt], 0, 0, 0);
          acc[tb][mt] = __builtin_amdgcn_mfma_f32_16x16x32_bf16(Al[f].v, Bh[tb][ks].v, acc[tb][mt], 0, 0, 0);
        }
      }

    if (l == N_LAYER - 1) break;

    // split-repack C/D -> next-layer Bh/Bl (same index map as verified chain)
    #pragma unroll
    for (int tb = 0; tb < 4; tb++)
      #pragma unroll
      for (int mt = 0; mt < 4; mt++) {
        const int ksn = mt >> 1;
        const int d   = 2 * (mt & 1);
        uint32_t u0 = pk_bf16(acc[tb][mt][0], acc[tb][mt][1]);
        uint32_t u1 = pk_bf16(acc[tb][mt][2], acc[tb][mt][3]);
        Bh[tb][ksn].u[d]     = u0;
        Bh[tb][ksn].u[d + 1] = u1;
        Bl[tb][ksn].u[d]     = pk_bf16(acc[tb][mt][0] - upk_lo(u0), acc[tb][mt][1] - upk_hi(u0));
        Bl[tb][ksn].u[d + 1] = pk_bf16(acc[tb][mt][2] - upk_lo(u1), acc[tb][mt][3] - upk_hi(u1));
      }
  }
  #undef FETCH

  // --- epilogue: natural-layout store to LDS (fp32), then build apply frags ---
  if (twv == 0) {
    #pragma unroll
    for (int tb = 0; tb < 4; tb++)
      #pragma unroll
      for (int mt = 0; mt < 4; mt++)
        *(floatx4*)&comp[tb * 16 + tl][32 * (mt >> 1) + 4 * (mt & 1) + 8 * q] = acc[tb][mt];
  } else if (tl == 0) {
    #pragma unroll
    for (int mt = 0; mt < 4; mt++)
      *(floatx4*)&comp[64][32 * (mt >> 1) + 4 * (mt & 1) + 8 * q] = acc[0][mt];
  }
  __syncthreads();

  // apply A-frags: A[m=ln&15][k=32ks+8q+j] = M[FPERM(mt,m)][k],
  // M[i][k] = comp[k][i] - v[i]
  for (int it = tid; it < 512; it += 128) {
    const int f  = it >> 6, ln = it & 63;
    const int mt = f >> 1,  ks = f & 1;
    const int m  = ln & 15, qq = ln >> 4;
    const int r  = FPERM(mt, m);
    const float vr = comp[64][r];
    union { uint16_t s[8]; uint4 v; } o;
    #pragma unroll
    for (int j = 0; j < 8; j++) o.s[j] = bf16_rne(comp[32 * ks + 8 * qq + j][r] - vr);
    *(uint4*)(afrag + (size_t)it * 8) = o.v;
  }
  if (tid < 64) vout[tid] = comp[64][tid];
}

// ---------------------------------------------------------------------------
// apply: out = M x + v. Pure streamer: 16 dwordx4 in, 32 MFMA, 16 dwordx4 out.
// ---------------------------------------------------------------------------
__global__ __launch_bounds__(256, 3) void apply_affine(
    const float* __restrict__ x, const uint16_t* __restrict__ afrag,
    const float* __restrict__ vvec, float* __restrict__ out)
{
  const int tid  = threadIdx.x;
  const int wv   = tid >> 6;
  const int lane = tid & 63;
  const int tl   = lane & 15;
  const int q    = lane >> 4;
  const int tokbase = blockIdx.x * 256 + wv * 64;

  // M frags (8 KB, L1-broadcast across waves)
  const uint4* wp = (const uint4*)afrag;
  AFrag Af[8];
  #pragma unroll
  for (int f = 0; f < 8; f++) Af[f].raw = wp[f * 64 + lane];

  // v at permuted acc positions
  floatx4 bv[4];
  #pragma unroll
  for (int mt = 0; mt < 4; mt++)
    bv[mt] = *(const floatx4*)(vvec + 32 * (mt >> 1) + 4 * (mt & 1) + 8 * q);

  // x -> B-frags
  BFrag Bf[4][2];
  #pragma unroll
  for (int tb = 0; tb < 4; tb++) {
    const float* xp = x + (size_t)(tokbase + tb * 16 + tl) * 64 + 8 * q;
    #pragma unroll
    for (int ks = 0; ks < 2; ks++) {
      floatx4 a0 = *(const floatx4*)(xp + 32 * ks);
      floatx4 a1 = *(const floatx4*)(xp + 32 * ks + 4);
      Bf[tb][ks].u[0] = pk_bf16(a0[0], a0[1]);
      Bf[tb][ks].u[1] = pk_bf16(a0[2], a0[3]);
      Bf[tb][ks].u[2] = pk_bf16(a1[0], a1[1]);
      Bf[tb][ks].u[3] = pk_bf16(a1[2], a1[3]);
    }
  }

  floatx4 acc[4][4];
  #pragma unroll
  for (int tb = 0; tb < 4; tb++)
    #pragma unroll
    for (int mt = 0; mt < 4; mt++) acc[tb][mt] = bv[mt];

  #pragma unroll
  for (int ks = 0; ks < 2; ks++)
    #pragma unroll
    for (int mt = 0; mt < 4; mt++)
      #pragma unroll
      for (int tb = 0; tb < 4; tb++)
        acc[tb][mt] = __builtin_amdgcn_mfma_f32_16x16x32_bf16(
            Af[mt * 2 + ks].v, Bf[tb][ks].v, acc[tb][mt], 0, 0, 0);

  // store (un-permuting, verified layout)
  #pragma unroll
  for (int tb = 0; tb < 4; tb++) {
    float* op = out + (size_t)(tokbase + tb * 16 + tl) * 64;
    #pragma unroll
    for (int mt = 0; mt < 4; mt++)
      *(floatx4*)(op + 32 * (mt >> 1) + 4 * (mt & 1) + 8 * q) = acc[tb][mt];
  }
}

extern "C" void kernel_launch(void* const* d_in, const int* in_sizes, int n_in,
                              void* d_out, int out_size, void* d_ws, size_t ws_size,
                              hipStream_t stream) {
  (void)in_sizes; (void)n_in; (void)out_size; (void)ws_size;
  const float* x = (const float*)d_in[0];
  const float* W = (const float*)d_in[1];   // [20][64][64] fp32
  const float* b = (const float*)d_in[2];   // [20][64] fp32
  float* out = (float*)d_out;

  uint16_t* afrag = (uint16_t*)d_ws;                 // 8192 B: M A-frags (bf16)
  float*    vvec  = (float*)((char*)d_ws + 8192);    // 256 B: composed bias v

  compose<<<dim3(1), dim3(128), 0, stream>>>(W, b, afrag, vvec);
  apply_affine<<<dim3(N_TOK / 256), dim3(256), 0, stream>>>(x, afrag, vvec, out);
}

// Round 4
// 275.711 us; speedup vs baseline: 1.3637x; 1.3637x over previous
//
#include <hip/hip_runtime.h>
#include <stdint.h>

// MissModel: chain of 20 x Linear(64,64) == ONE affine map out = M x + v,
//   M = W19···W0,  v = sum of suffix-products of biases.
// R4: three kernels.
//  1) prep_split (parallel): fp32 W -> split bf16 (hi + residual lo) A-frags
//     for all 20 layers, in the FPERM-permuted MFMA A layout. 320 KB to ws.
//  2) compose (1 block, 2 waves): serial 20-layer split-bf16 chain over 64
//     basis vectors (wave 0) + zero vector (wave 1 -> v). Uses the R2-proven
//     register prefetch/copy pattern (no dynamically-indexed reg arrays ->
//     no scratch spill). Epilogue emits apply A-frags + v.
//  3) apply (grid): out = M x + v. 32 tokens/wave, 16 waves/CU, HBM-bound.

using short8  = __attribute__((ext_vector_type(8))) short;  // 8 bf16
using floatx4 = __attribute__((ext_vector_type(4))) float;  // MFMA 16x16 acc

#define N_TOK   524288
#define N_LAYER 20
// output-feature permutation baked into A-frag rows (verified R1-R3)
#define FPERM(mt, m) (32 * ((mt) >> 1) + 8 * ((m) >> 2) + 4 * ((mt) & 1) + ((m) & 3))

#ifdef __has_builtin
#if __has_builtin(__builtin_amdgcn_cvt_pk_bf16_f32)
#define HAVE_CVT_PK_BF16 1
#endif
#endif

#ifdef HAVE_CVT_PK_BF16
typedef __bf16 bf16x2_t __attribute__((ext_vector_type(2)));
__device__ __forceinline__ uint32_t pk_bf16(float lo, float hi) {
  union { bf16x2_t v; uint32_t u; } c;
  c.v = __builtin_amdgcn_cvt_pk_bf16_f32(lo, hi);   // RNE, 1 VALU
  return c.u;
}
#else
__device__ __forceinline__ uint32_t pk_bf16(float lo, float hi) {
  uint32_t a = __float_as_uint(lo) + 0x8000u;
  uint32_t b = __float_as_uint(hi) + 0x8000u;
  return __builtin_amdgcn_perm(b, a, 0x07060302u);
}
#endif

__device__ __forceinline__ float upk_lo(uint32_t p) { return __uint_as_float(p << 16); }
__device__ __forceinline__ float upk_hi(uint32_t p) { return __uint_as_float(p & 0xffff0000u); }

__device__ __forceinline__ uint16_t bf16_rne(float f) {
  uint32_t u = __float_as_uint(f);
  u += 0x7fffu + ((u >> 16) & 1u);
  return (uint16_t)(u >> 16);
}
__device__ __forceinline__ float bf16_dec(uint16_t h) {
  return __uint_as_float(((uint32_t)h) << 16);
}

union BFrag { short8 v; uint32_t u[4]; };
union AFrag { short8 v; uint32_t u[4]; uint4 raw; };

// ---------------------------------------------------------------------------
// prep_split: W fp32 [20][64][64] -> hi frags (wsh) + residual lo frags (wsl).
// Frag f=mt*2+ks of layer l at [(l*8+f)*64 + lane], 16 B per lane.
// Lane holds A[m=lane&15][k=32*ks+8*(lane>>4)+j], row m = FPERM(mt,m) of W.
// idx space: 20 layers * 8 frags * 64 lanes = 10240.
// ---------------------------------------------------------------------------
__global__ void prep_split(const float* __restrict__ W,
                           uint16_t* __restrict__ wsh, uint16_t* __restrict__ wsl) {
  int idx  = blockIdx.x * 256 + threadIdx.x;   // [0, 10240)
  int l    = idx >> 9;
  int rem  = idx & 511;
  int frag = rem >> 6;
  int lane = rem & 63;
  int mt = frag >> 1, ks = frag & 1;
  int m  = lane & 15;
  int q  = lane >> 4;
  int wrow = FPERM(mt, m);
  const float* src = W + l * 4096 + wrow * 64 + 32 * ks + 8 * q;
  float4 f0 = *(const float4*)(src);
  float4 f1 = *(const float4*)(src + 4);
  float w[8] = {f0.x, f0.y, f0.z, f0.w, f1.x, f1.y, f1.z, f1.w};
  union { uint16_t s[8]; uint4 v; } oh, ol;
  #pragma unroll
  for (int j = 0; j < 8; j++) {
    uint16_t h = bf16_rne(w[j]);
    oh.s[j] = h;
    ol.s[j] = bf16_rne(w[j] - bf16_dec(h));
  }
  *(uint4*)(wsh + (size_t)idx * 8) = oh.v;
  *(uint4*)(wsl + (size_t)idx * 8) = ol.v;
}

// ---------------------------------------------------------------------------
// compose: 1 block, 128 threads. Wave 0 tokens = I_64 columns, wave 1 = 0
// (carries v). Split chain: 3 MFMA products per k-step
// (Wh*Hh + Wh*Hl + Wl*Hh). R2-style prefetch (nf regs -> copy) -- no scratch.
// ---------------------------------------------------------------------------
__global__ __launch_bounds__(128, 1) void compose(
    const uint16_t* __restrict__ wsh, const uint16_t* __restrict__ wsl,
    const float* __restrict__ bias,
    uint16_t* __restrict__ afrag, float* __restrict__ vout)
{
  __shared__ float comp[65][64];                 // comp[t][i]=(M e_t + v)[i]; comp[64]=v
  __shared__ __align__(16) float biasLds[N_LAYER * 64];

  const int tid  = threadIdx.x;
  const int twv  = tid >> 6;
  const int lane = tid & 63;
  const int tl   = lane & 15;
  const int q    = lane >> 4;

  for (int i = tid; i < N_LAYER * 64; i += 128) biasLds[i] = bias[i];

  // basis-vector state (wave0: hi = identity; wave1: zero)
  BFrag Bh[4][2], Bl[4][2];
  #pragma unroll
  for (int tb = 0; tb < 4; tb++) {
    const int tok = twv * 64 + tb * 16 + tl;     // wave1 toks 64..127: never match
    #pragma unroll
    for (int ks = 0; ks < 2; ks++)
      #pragma unroll
      for (int p = 0; p < 4; p++) {
        const int f0 = 32 * ks + 8 * q + 2 * p;
        Bh[tb][ks].u[p] = pk_bf16(tok == f0 ? 1.0f : 0.0f, tok == f0 + 1 ? 1.0f : 0.0f);
        Bl[tb][ks].u[p] = 0u;
      }
  }

  const uint4* wph = (const uint4*)wsh;
  const uint4* wpl = (const uint4*)wsl;

  // layer-0 frags
  AFrag Ah[8], Al[8];
  #pragma unroll
  for (int f = 0; f < 8; f++) {
    Ah[f].raw = wph[f * 64 + lane];
    Al[f].raw = wpl[f * 64 + lane];
  }

  __syncthreads();   // biasLds ready

  floatx4 acc[4][4];
  #pragma unroll 2
  for (int l = 0; l < N_LAYER; l++) {
    const int ln = (l + 1 < N_LAYER) ? l + 1 : N_LAYER - 1;
    uint4 nh[8], nl[8];
    #pragma unroll
    for (int f = 0; f < 8; f++) {
      nh[f] = wph[(ln * 8 + f) * 64 + lane];
      nl[f] = wpl[(ln * 8 + f) * 64 + lane];
    }

    // acc init = bias at permuted positions (same for all tokens: h' = Wh + b)
    #pragma unroll
    for (int mt = 0; mt < 4; mt++) {
      floatx4 bv = *(const floatx4*)(biasLds + l * 64 + 32 * (mt >> 1) + 4 * (mt & 1) + 8 * q);
      #pragma unroll
      for (int tb = 0; tb < 4; tb++) acc[tb][mt] = bv;
    }

    #pragma unroll
    for (int ks = 0; ks < 2; ks++)
      #pragma unroll
      for (int mt = 0; mt < 4; mt++) {
        const int f = mt * 2 + ks;
        #pragma unroll
        for (int tb = 0; tb < 4; tb++) {
          acc[tb][mt] = __builtin_amdgcn_mfma_f32_16x16x32_bf16(Ah[f].v, Bh[tb][ks].v, acc[tb][mt], 0, 0, 0);
          acc[tb][mt] = __builtin_amdgcn_mfma_f32_16x16x32_bf16(Ah[f].v, Bl[tb][ks].v, acc[tb][mt], 0, 0, 0);
          acc[tb][mt] = __builtin_amdgcn_mfma_f32_16x16x32_bf16(Al[f].v, Bh[tb][ks].v, acc[tb][mt], 0, 0, 0);
        }
      }

    if (l == N_LAYER - 1) break;

    // split repack C/D -> next-layer Bh/Bl
    #pragma unroll
    for (int tb = 0; tb < 4; tb++)
      #pragma unroll
      for (int mt = 0; mt < 4; mt++) {
        const int ksn = mt >> 1;
        const int d   = 2 * (mt & 1);
        uint32_t u0 = pk_bf16(acc[tb][mt][0], acc[tb][mt][1]);
        uint32_t u1 = pk_bf16(acc[tb][mt][2], acc[tb][mt][3]);
        Bh[tb][ksn].u[d]     = u0;
        Bh[tb][ksn].u[d + 1] = u1;
        Bl[tb][ksn].u[d]     = pk_bf16(acc[tb][mt][0] - upk_lo(u0), acc[tb][mt][1] - upk_hi(u0));
        Bl[tb][ksn].u[d + 1] = pk_bf16(acc[tb][mt][2] - upk_lo(u1), acc[tb][mt][3] - upk_hi(u1));
      }

    // rotate in prefetched frags (register rename under unroll-2)
    #pragma unroll
    for (int f = 0; f < 8; f++) { Ah[f].raw = nh[f]; Al[f].raw = nl[f]; }
  }

  // epilogue: natural-layout store to LDS, then build apply frags + v
  if (twv == 0) {
    #pragma unroll
    for (int tb = 0; tb < 4; tb++)
      #pragma unroll
      for (int mt = 0; mt < 4; mt++)
        *(floatx4*)&comp[tb * 16 + tl][32 * (mt >> 1) + 4 * (mt & 1) + 8 * q] = acc[tb][mt];
  } else if (tl == 0) {
    #pragma unroll
    for (int mt = 0; mt < 4; mt++)
      *(floatx4*)&comp[64][32 * (mt >> 1) + 4 * (mt & 1) + 8 * q] = acc[0][mt];
  }
  __syncthreads();

  // apply A-frags: A[m][k] = M[FPERM(mt,m)][k]; M[i][k] = comp[k][i] - v[i]
  for (int it = tid; it < 512; it += 128) {
    const int f  = it >> 6, ln = it & 63;
    const int mt = f >> 1,  ks = f & 1;
    const int m  = ln & 15, qq = ln >> 4;
    const int r  = FPERM(mt, m);
    const float vr = comp[64][r];
    union { uint16_t s[8]; uint4 v; } o;
    #pragma unroll
    for (int j = 0; j < 8; j++) o.s[j] = bf16_rne(comp[32 * ks + 8 * qq + j][r] - vr);
    *(uint4*)(afrag + (size_t)it * 8) = o.v;
  }
  if (tid < 64) vout[tid] = comp[64][tid];
}

// ---------------------------------------------------------------------------
// apply: out = M x + v. 32 tokens/wave (slim regs -> 4 waves/EU), 4096 blocks.
// ---------------------------------------------------------------------------
__global__ __launch_bounds__(256, 4) void apply_affine(
    const float* __restrict__ x, const uint16_t* __restrict__ afrag,
    const float* __restrict__ vvec, float* __restrict__ out)
{
  const int tid  = threadIdx.x;
  const int wv   = tid >> 6;
  const int lane = tid & 63;
  const int tl   = lane & 15;
  const int q    = lane >> 4;
  const int tokbase = blockIdx.x * 128 + wv * 32;

  // M frags (8 KB, L1-broadcast across waves/blocks)
  const uint4* wp = (const uint4*)afrag;
  AFrag Af[8];
  #pragma unroll
  for (int f = 0; f < 8; f++) Af[f].raw = wp[f * 64 + lane];

  // v at permuted acc positions
  floatx4 bv[4];
  #pragma unroll
  for (int mt = 0; mt < 4; mt++)
    bv[mt] = *(const floatx4*)(vvec + 32 * (mt >> 1) + 4 * (mt & 1) + 8 * q);

  // x -> B-frags (2 token-blocks of 16)
  BFrag Bf[2][2];
  #pragma unroll
  for (int tb = 0; tb < 2; tb++) {
    const float* xp = x + (size_t)(tokbase + tb * 16 + tl) * 64 + 8 * q;
    #pragma unroll
    for (int ks = 0; ks < 2; ks++) {
      floatx4 a0 = *(const floatx4*)(xp + 32 * ks);
      floatx4 a1 = *(const floatx4*)(xp + 32 * ks + 4);
      Bf[tb][ks].u[0] = pk_bf16(a0[0], a0[1]);
      Bf[tb][ks].u[1] = pk_bf16(a0[2], a0[3]);
      Bf[tb][ks].u[2] = pk_bf16(a1[0], a1[1]);
      Bf[tb][ks].u[3] = pk_bf16(a1[2], a1[3]);
    }
  }

  floatx4 acc[2][4];
  #pragma unroll
  for (int tb = 0; tb < 2; tb++)
    #pragma unroll
    for (int mt = 0; mt < 4; mt++) acc[tb][mt] = bv[mt];

  #pragma unroll
  for (int ks = 0; ks < 2; ks++)
    #pragma unroll
    for (int mt = 0; mt < 4; mt++)
      #pragma unroll
      for (int tb = 0; tb < 2; tb++)
        acc[tb][mt] = __builtin_amdgcn_mfma_f32_16x16x32_bf16(
            Af[mt * 2 + ks].v, Bf[tb][ks].v, acc[tb][mt], 0, 0, 0);

  #pragma unroll
  for (int tb = 0; tb < 2; tb++) {
    float* op = out + (size_t)(tokbase + tb * 16 + tl) * 64;
    #pragma unroll
    for (int mt = 0; mt < 4; mt++)
      *(floatx4*)(op + 32 * (mt >> 1) + 4 * (mt & 1) + 8 * q) = acc[tb][mt];
  }
}

extern "C" void kernel_launch(void* const* d_in, const int* in_sizes, int n_in,
                              void* d_out, int out_size, void* d_ws, size_t ws_size,
                              hipStream_t stream) {
  (void)in_sizes; (void)n_in; (void)out_size; (void)ws_size;
  const float* x = (const float*)d_in[0];
  const float* W = (const float*)d_in[1];   // [20][64][64] fp32
  const float* b = (const float*)d_in[2];   // [20][64] fp32
  float* out = (float*)d_out;

  uint16_t* wsh   = (uint16_t*)d_ws;                     // 160 KB hi frags
  uint16_t* wsl   = (uint16_t*)((char*)d_ws + 163840);   // 160 KB lo frags
  uint16_t* afrag = (uint16_t*)((char*)d_ws + 327680);   // 8 KB composed M frags
  float*    vvec  = (float*)((char*)d_ws + 335872);      // 256 B composed v

  prep_split<<<dim3(40), dim3(256), 0, stream>>>(W, wsh, wsl);
  compose<<<dim3(1), dim3(128), 0, stream>>>(wsh, wsl, b, afrag, vvec);
  apply_affine<<<dim3(N_TOK / 128), dim3(256), 0, stream>>>(x, afrag, vvec, out);
}